// Round 6
// baseline (114.546 us; speedup 1.0000x reference)
//
#include <hip/hip_runtime.h>
#include <hip/hip_bf16.h>
#include <cstdint>
#include <cstddef>

// RBF Gram matrix: K[i,j] = exp(-gamma * max(||a_i||^2 + ||b_j||^2 - 2 a_i.b_j, 0))
// A: [8192,256] f32, B: [8192,256] f32, Out: [8192,8192] f32.
//
// Round-6 theory: all previous variants (89-99us) were DRAM-page-activate
// bound on the C write: 128x128 tiles emit 512B row-runs 32KB apart
// (~3.2 TB/s effective). Fix = tile geometry 32x512 (2KB contiguous runs)
// + row-major LDS-staged flush (1KB per wave store instruction), all waves
// participating. K-loop: single-buffered serial (round-2 structure, fastest
// measured). Each XCD owns a 2-tile-col band (B panel 512KB, L2 resident).

#define GAMMA_F 0.00390625f

typedef __attribute__((ext_vector_type(8))) short short8;   // 8 bf16
typedef __attribute__((ext_vector_type(4))) float f32x4;    // acc / 16B

constexpr int KD = 256;
constexpr int ND = 8192;
constexpr int BM = 32, BN = 512, BK = 32;
// grid: (8192/32) x (8192/512) = 256 x 16 = 4096 blocks

__device__ __forceinline__ unsigned short f2b(float f) {
  unsigned int u = __float_as_uint(f);
  u += 0x7FFFu + ((u >> 16) & 1u);
  return (unsigned short)(u >> 16);
}

__device__ __forceinline__ void gload_lds16(const void* g, void* l) {
  __builtin_amdgcn_global_load_lds(
      (const __attribute__((address_space(1))) unsigned int*)g,
      (__attribute__((address_space(3))) unsigned int*)l, 16, 0, 0);
}

// ---------------------------------------------------------------------------
// Prepass: row L2-norms (f32) + bf16 convert. One wave per row.
// ---------------------------------------------------------------------------
__global__ __launch_bounds__(256) void norm_convert_kernel(
    const float* __restrict__ A, const float* __restrict__ B,
    unsigned short* Abf, unsigned short* Bbf,
    float* __restrict__ asq, float* __restrict__ bsq)
{
  const int lane = threadIdx.x & 63;
  const int row = blockIdx.x * 4 + (threadIdx.x >> 6);
  const float* src = A;
  unsigned short* dst = Abf;
  float* nrm = asq;
  int r = row;
  if (row >= ND) { src = B; dst = Bbf; nrm = bsq; r = row - ND; }

  const float4 v = *(const float4*)(src + (size_t)r * KD + lane * 4);
  float s = v.x * v.x + v.y * v.y + v.z * v.z + v.w * v.w;
  #pragma unroll
  for (int off = 32; off >= 1; off >>= 1) s += __shfl_xor(s, off, 64);

  if (dst) {
    const unsigned int p0 = (unsigned)f2b(v.x) | ((unsigned)f2b(v.y) << 16);
    const unsigned int p1 = (unsigned)f2b(v.z) | ((unsigned)f2b(v.w) << 16);
    *(uint2*)(dst + (size_t)r * KD + lane * 4) = make_uint2(p0, p1);
  }
  if (lane == 0) nrm[r] = s;
}

// ---------------------------------------------------------------------------
// Main GEMM + RBF epilogue, 32x512 tile. 256 threads = 4 waves; wave w owns
// cols [w*128, w*128+128): fragments acc[fm<2][fn<8] (16 MFMA / K-step).
//
// LDS (34 KiB): A-tile [32][64B] at 0, B-tile [512][64B] at 2048. Staging via
// linear-dest global_load_lds with the GLOBAL-SOURCE permuted by the
// involution f(b)=b^(((b>>7)&3)<<4); ds_read applies the same XOR (both-
// sides-or-neither). Fragment reads: 2 lanes/bank = conflict-free.
// Epilogue reuses LDS [0,32KiB) as a 16-row x 2048B row-major buffer.
// ---------------------------------------------------------------------------
template <bool BF16WS>
__global__ __launch_bounds__(256) void rbf_gemm_kernel(
    const void* __restrict__ Aop, const void* __restrict__ Bop,
    const float* __restrict__ asq, const float* __restrict__ bsq,
    float* __restrict__ C)
{
  __shared__ __align__(16) char smem[34816];
  const int t = threadIdx.x;
  const int lane = t & 63;
  const int wid = t >> 6;

  // XCD mapping: x = bid&7 (HW round-robin), k = bid>>3 walks the XCD's
  // blocks. Each XCD owns tile-cols {2x, 2x+1} (B rows [1024x,1024x+1024),
  // 512KB bf16, L2-resident) x all 256 tile-rows. k&1 toggles col (A-tile
  // reused across the pair), k>>1 = tile row. Bijective: 8*512 = 4096.
  const int bid = blockIdx.x;
  const int x = bid & 7;
  const int k = bid >> 3;
  const int brow = (k >> 1) << 5;                 // tile row * 32
  const int bcol = (((x << 1) | (k & 1))) << 9;   // tile col * 512

  // Staging: dest byte d (linear), source = f(d): row = d>>6 unchanged,
  // col-slot XORed. For d = t*16 + it*4096: (d>>7)&3 = (t>>3)&3 (it*32%4=0).
  const int scolb = (((t & 3) ^ ((t >> 3) & 3)) << 4);

  // Fragment ds_read offsets.
  int aoff[2], boff[8];
  #pragma unroll
  for (int fm = 0; fm < 2; ++fm) {
    const int ra = fm * 16 + (lane & 15);
    aoff[fm] = ra * 64 + (((lane >> 4) * 16) ^ (((ra >> 1) & 3) << 4));
  }
  #pragma unroll
  for (int fn = 0; fn < 8; ++fn) {
    const int rb = wid * 128 + fn * 16 + (lane & 15);
    boff[fn] = 2048 + rb * 64 + (((lane >> 4) * 16) ^ (((rb >> 1) & 3) << 4));
  }

  const char* Ab = (const char*)Aop;
  const char* Bb = (const char*)Bop;
  const float* Af = (const float*)Aop;
  const float* Bf = (const float*)Bop;

  f32x4 acc[2][8] = {};

  for (int kt = 0; kt < KD / BK; ++kt) {
    // ---- stage (serial single-buffer; round-2 structure) ----
    if constexpr (BF16WS) {
      // B: 8 chunks x 256 threads x 16B = 32KB
      #pragma unroll
      for (int it = 0; it < 8; ++it) {
        const int row = it * 64 + (t >> 2);
        gload_lds16(Bb + (size_t)(bcol + row) * (KD * 2) + kt * (BK * 2) + scolb,
                    smem + 2048 + it * 4096 + wid * 1024);
      }
      // A: 2KB, waves 0-1 only (wave-uniform branch)
      if (wid < 2) {
        gload_lds16(Ab + (size_t)(brow + (t >> 2)) * (KD * 2) + kt * (BK * 2) + scolb,
                    smem + wid * 1024);
      }
    } else {
      #pragma unroll
      for (int it = 0; it < 8; ++it) {
        const int row = it * 64 + (t >> 2);
        const float* sb = Bf + (size_t)(bcol + row) * KD + kt * BK + (scolb >> 1);
        const float4 b0 = *(const float4*)sb;
        const float4 b1 = *(const float4*)(sb + 4);
        *(uint4*)(smem + 2048 + it * 4096 + t * 16) = make_uint4(
            (unsigned)f2b(b0.x) | ((unsigned)f2b(b0.y) << 16),
            (unsigned)f2b(b0.z) | ((unsigned)f2b(b0.w) << 16),
            (unsigned)f2b(b1.x) | ((unsigned)f2b(b1.y) << 16),
            (unsigned)f2b(b1.z) | ((unsigned)f2b(b1.w) << 16));
      }
      if (t < 128) {
        const float* sa = Af + (size_t)(brow + (t >> 2)) * KD + kt * BK + (scolb >> 1);
        const float4 a0 = *(const float4*)sa;
        const float4 a1 = *(const float4*)(sa + 4);
        *(uint4*)(smem + t * 16) = make_uint4(
            (unsigned)f2b(a0.x) | ((unsigned)f2b(a0.y) << 16),
            (unsigned)f2b(a0.z) | ((unsigned)f2b(a0.w) << 16),
            (unsigned)f2b(a1.x) | ((unsigned)f2b(a1.y) << 16),
            (unsigned)f2b(a1.z) | ((unsigned)f2b(a1.w) << 16));
      }
    }
    __syncthreads();

    // ---- compute ----
    short8 af[2], bfv[8];
    #pragma unroll
    for (int fm = 0; fm < 2; ++fm) af[fm] = *(const short8*)(smem + aoff[fm]);
    #pragma unroll
    for (int fn = 0; fn < 8; ++fn) bfv[fn] = *(const short8*)(smem + boff[fn]);
    // Swapped operands: thread holds C[i][j0..j0+3], i = brow+fm*16+(lane&15),
    // j0 = bcol + wid*128 + fn*16 + (lane>>4)*4.
    #pragma unroll
    for (int fm = 0; fm < 2; ++fm)
      #pragma unroll
      for (int fn = 0; fn < 8; ++fn)
        acc[fm][fn] = __builtin_amdgcn_mfma_f32_16x16x32_bf16(
            bfv[fn], af[fm], acc[fm][fn], 0, 0, 0);

    __syncthreads();
  }

  // ---- epilogue: exp through LDS, row-major page-friendly flush ----
  // Pass p = fragment row-block fm=p: 16 rows x 2048B = 32KB in LDS
  // (staging buffers dead). All 4 waves write their 8 fragments, then all
  // 256 threads flush 2 rows/iter: per wave instruction 64 lanes x 16B =
  // 1KB contiguous; full rows are 2KB contiguous in C.
  const float cexp = -GAMMA_F * 1.44269504088896340736f;
  #pragma unroll
  for (int p = 0; p < 2; ++p) {
    __syncthreads();
    {
      const int rl = lane & 15;
      const float an = asq[brow + p * 16 + rl];
      #pragma unroll
      for (int fn = 0; fn < 8; ++fn) {
        const int jl = wid * 512 + fn * 64 + ((lane >> 4) << 4);  // byte col
        const f32x4 b4 = *(const f32x4*)&bsq[bcol + (jl >> 2)];
        f32x4 o;
        o[0] = exp2f(fmaxf(an + b4[0] - 2.0f * acc[p][fn][0], 0.0f) * cexp);
        o[1] = exp2f(fmaxf(an + b4[1] - 2.0f * acc[p][fn][1], 0.0f) * cexp);
        o[2] = exp2f(fmaxf(an + b4[2] - 2.0f * acc[p][fn][2], 0.0f) * cexp);
        o[3] = exp2f(fmaxf(an + b4[3] - 2.0f * acc[p][fn][3], 0.0f) * cexp);
        *(f32x4*)(smem + rl * 2048 + (jl ^ ((rl & 7) << 4))) = o;
      }
    }
    __syncthreads();
    #pragma unroll
    for (int it = 0; it < 8; ++it) {
      const int rl = it * 2 + (t >> 7);
      const int cb = (t & 127) * 16;
      const f32x4 v = *(const f32x4*)(smem + rl * 2048 + (cb ^ ((rl & 7) << 4)));
      __builtin_nontemporal_store(
          v, (f32x4*)(C + (size_t)(brow + p * 16 + rl) * ND + bcol + (t & 127) * 4));
    }
  }
}

// ---------------------------------------------------------------------------
extern "C" void kernel_launch(void* const* d_in, const int* in_sizes, int n_in,
                              void* d_out, int out_size, void* d_ws, size_t ws_size,
                              hipStream_t stream) {
  const float* A = (const float*)d_in[0];
  const float* B = (const float*)d_in[1];
  float* C = (float*)d_out;

  const size_t bfBytes = (size_t)ND * KD * 2;   // 4 MiB per matrix
  const size_t normBytes = (size_t)ND * 4;
  char* ws = (char*)d_ws;
  const int grid = (ND / BM) * (ND / BN);       // 4096

  if (ws_size >= 2 * bfBytes + 2 * normBytes) {
    unsigned short* Abf = (unsigned short*)ws;
    unsigned short* Bbf = (unsigned short*)(ws + bfBytes);
    float* asq = (float*)(ws + 2 * bfBytes);
    float* bsq = (float*)(ws + 2 * bfBytes + normBytes);
    hipLaunchKernelGGL(norm_convert_kernel, dim3(2 * ND / 4), dim3(256), 0, stream,
                       A, B, Abf, Bbf, asq, bsq);
    hipLaunchKernelGGL((rbf_gemm_kernel<true>), dim3(grid), dim3(256), 0,
                       stream, (const void*)Abf, (const void*)Bbf, asq, bsq, C);
  } else {
    float* asq = (float*)ws;
    float* bsq = (float*)(ws + normBytes);
    hipLaunchKernelGGL(norm_convert_kernel, dim3(2 * ND / 4), dim3(256), 0, stream,
                       A, B, (unsigned short*)nullptr, (unsigned short*)nullptr, asq, bsq);
    hipLaunchKernelGGL((rbf_gemm_kernel<false>), dim3(grid), dim3(256), 0,
                       stream, (const void*)A, (const void*)B, asq, bsq, C);
  }
}

// Round 7
// 87.528 us; speedup vs baseline: 1.3087x; 1.3087x over previous
//
#include <hip/hip_runtime.h>
#include <hip/hip_bf16.h>
#include <cstdint>
#include <cstddef>

// RBF Gram matrix: K[i,j] = exp(-gamma * max(||a_i||^2 + ||b_j||^2 - 2 a_i.b_j, 0))
// A: [8192,256] f32, B: [8192,256] f32, Out: [8192,8192] f32.
//
// Round-7: break store/compute phase-lock. All one-tile-per-block variants
// (89-115us) match a serial component model where the ~39us of C stores never
// overlap compute (phase-locked block lifecycles). Changes vs round-4:
//  * 4 tiles per block (grid 1024, 4 consecutive tile-cols, same tile-row):
//    tile t+1's first K-stage is issued BEFORE tile t's epilogue, and tile
//    t's stores drain under tile t+1's K-loop -> structural overlap.
//  * Plain (non-nt) stores: L2 acks fast (cheap vmcnt drains at barriers),
//    merges 64B segments into full lines, streams to HBM in background
//    (needed 3-4 TB/s < 6.9 ceiling). L3 backstops panel evictions.
// K-loop, staging involution, swapped-operand MFMA unchanged (verified).

#define GAMMA_F 0.00390625f

typedef __attribute__((ext_vector_type(8))) short short8;   // 8 bf16
typedef __attribute__((ext_vector_type(4))) float f32x4;    // acc / 16B

constexpr int KD = 256;
constexpr int ND = 8192;
constexpr int BM = 128, BN = 128, BK = 32;
constexpr int TPB = 4;     // tiles per block (consecutive tile-cols)
// grid = (64 * 64) / 4 = 1024 blocks

__device__ __forceinline__ unsigned short f2b(float f) {
  unsigned int u = __float_as_uint(f);
  u += 0x7FFFu + ((u >> 16) & 1u);
  return (unsigned short)(u >> 16);
}

__device__ __forceinline__ void gload_lds16(const void* g, void* l) {
  __builtin_amdgcn_global_load_lds(
      (const __attribute__((address_space(1))) unsigned int*)g,
      (__attribute__((address_space(3))) unsigned int*)l, 16, 0, 0);
}

// ---------------------------------------------------------------------------
// Prepass: row L2-norms (f32) + bf16 convert. One wave per row.
// ---------------------------------------------------------------------------
__global__ __launch_bounds__(256) void norm_convert_kernel(
    const float* __restrict__ A, const float* __restrict__ B,
    unsigned short* Abf, unsigned short* Bbf,
    float* __restrict__ asq, float* __restrict__ bsq)
{
  const int lane = threadIdx.x & 63;
  const int row = blockIdx.x * 4 + (threadIdx.x >> 6);
  const float* src = A;
  unsigned short* dst = Abf;
  float* nrm = asq;
  int r = row;
  if (row >= ND) { src = B; dst = Bbf; nrm = bsq; r = row - ND; }

  const float4 v = *(const float4*)(src + (size_t)r * KD + lane * 4);
  float s = v.x * v.x + v.y * v.y + v.z * v.z + v.w * v.w;
  #pragma unroll
  for (int off = 32; off >= 1; off >>= 1) s += __shfl_xor(s, off, 64);

  if (dst) {
    const unsigned int p0 = (unsigned)f2b(v.x) | ((unsigned)f2b(v.y) << 16);
    const unsigned int p1 = (unsigned)f2b(v.z) | ((unsigned)f2b(v.w) << 16);
    *(uint2*)(dst + (size_t)r * KD + lane * 4) = make_uint2(p0, p1);
  }
  if (lane == 0) nrm[r] = s;
}

// ---------------------------------------------------------------------------
// Main GEMM + RBF epilogue. 256 threads = 4 waves (2x2); each wave owns a
// 64x64 sub-tile (acc[4][4] of 16x16 fragments). BK=32 -> 8 K-steps,
// 2-phase double-buffered LDS. Each block walks TPB=4 tiles along one
// tile-row (A-panel reuse; stores of tile t drain under tile t+1 compute).
//
// LDS staging: linear global_load_lds dest; GLOBAL source permuted by the
// involution f(b)=b^(((b>>7)&3)<<4); ds_read applies the same XOR (rule
// #21, both-sides-or-neither). Fragment reads 2 lanes/bank = conflict-free.
// ---------------------------------------------------------------------------
template <bool BF16WS>
__global__ __launch_bounds__(256) void rbf_gemm_kernel(
    const void* __restrict__ Aop, const void* __restrict__ Bop,
    const float* __restrict__ asq, const float* __restrict__ bsq,
    float* __restrict__ C)
{
  __shared__ __align__(16) char smem[32768];
  const int t = threadIdx.x;
  const int lane = t & 63;
  const int wid = t >> 6;
  const int wm = wid >> 1, wn = wid & 1;

  // XCD mapping (bijective, 8 XCDs x 128 blocks): each XCD owns a
  // 16-tile-row x 8-tile-quad region => per-XCD L2 working set =
  // 2MB B-panel + 1MB A-panel (< 4MB L2).
  const int bid = blockIdx.x;
  const int x = bid & 7;
  const int k = bid >> 3;                  // 0..127
  const int tr = ((x >> 1) << 4) + (k >> 3);          // tile row 0..63
  const int tcq = ((x & 1) << 3) + (k & 7);           // tile quad 0..15
  const int brow = tr << 7;
  const int tc0 = tcq << 2;                           // first tile col

  // Staging coords: dest byte (per half h) = h*4096 + t*16; source = f(dest).
  const int srow = t >> 2;                                    // 0..63
  const int scolb = (((t & 3) ^ ((t >> 3) & 3)) << 4);        // swizzled col byte

  // Fragment ds_read offsets (buffer 0; add bufsel*8192 at use).
  int aoff[4], boff[4];
  #pragma unroll
  for (int f = 0; f < 4; ++f) {
    const int ra = wm * 64 + f * 16 + (lane & 15);
    aoff[f] = ra * 64 + (((lane >> 4) * 16) ^ (((ra >> 1) & 3) << 4));
    const int rb = wn * 64 + f * 16 + (lane & 15);
    boff[f] = 16384 + rb * 64 + (((lane >> 4) * 16) ^ (((rb >> 1) & 3) << 4));
  }

  const char* Ab = (const char*)Aop;
  const char* Bb = (const char*)Bop;
  const float* Af = (const float*)Aop;
  const float* Bf = (const float*)Bop;

  auto stage = [&](int buf, int kt, int bcol) {
    if constexpr (BF16WS) {
      #pragma unroll
      for (int h = 0; h < 2; ++h) {
        gload_lds16(Ab + (size_t)(brow + h * 64 + srow) * (KD * 2) + kt * (BK * 2) + scolb,
                    smem + buf * 8192 + h * 4096 + wid * 1024);
        gload_lds16(Bb + (size_t)(bcol + h * 64 + srow) * (KD * 2) + kt * (BK * 2) + scolb,
                    smem + 16384 + buf * 8192 + h * 4096 + wid * 1024);
      }
    } else {
      #pragma unroll
      for (int h = 0; h < 2; ++h) {
        const float* sa = Af + (size_t)(brow + h * 64 + srow) * KD + kt * BK + (scolb >> 1);
        const float4 a0 = *(const float4*)sa;
        const float4 a1 = *(const float4*)(sa + 4);
        *(uint4*)(smem + buf * 8192 + h * 4096 + t * 16) = make_uint4(
            (unsigned)f2b(a0.x) | ((unsigned)f2b(a0.y) << 16),
            (unsigned)f2b(a0.z) | ((unsigned)f2b(a0.w) << 16),
            (unsigned)f2b(a1.x) | ((unsigned)f2b(a1.y) << 16),
            (unsigned)f2b(a1.z) | ((unsigned)f2b(a1.w) << 16));
        const float* sb = Bf + (size_t)(bcol + h * 64 + srow) * KD + kt * BK + (scolb >> 1);
        const float4 b0 = *(const float4*)sb;
        const float4 b1 = *(const float4*)(sb + 4);
        *(uint4*)(smem + 16384 + buf * 8192 + h * 4096 + t * 16) = make_uint4(
            (unsigned)f2b(b0.x) | ((unsigned)f2b(b0.y) << 16),
            (unsigned)f2b(b0.z) | ((unsigned)f2b(b0.w) << 16),
            (unsigned)f2b(b1.x) | ((unsigned)f2b(b1.y) << 16),
            (unsigned)f2b(b1.z) | ((unsigned)f2b(b1.w) << 16));
      }
    }
  };

  const float cexp = -GAMMA_F * 1.44269504088896340736f;

  // ---- prologue: stage tile 0 / K-step 0 ----
  stage(0, 0, tc0 << 7);
  __syncthreads();

  for (int t4 = 0; t4 < TPB; ++t4) {
    const int bcol = (tc0 + t4) << 7;
    f32x4 acc[4][4] = {};

    // ---- 2-phase K-loop (kt=0 already staged) ----
    for (int kt = 0; kt < KD / BK; ++kt) {
      const int cur = kt & 1;
      if (kt + 1 < KD / BK) stage(cur ^ 1, kt + 1, bcol);

      const int cb = cur * 8192;
      short8 af[4], bfv[4];
      #pragma unroll
      for (int f = 0; f < 4; ++f) {
        af[f]  = *(const short8*)(smem + cb + aoff[f]);
        bfv[f] = *(const short8*)(smem + cb + boff[f]);
      }
      // Swapped operands: thread holds C[i][j0..j0+3],
      // i = brow+wm*64+fm*16+(lane&15), j0 = bcol+wn*64+fn*16+(lane>>4)*4.
      #pragma unroll
      for (int fm = 0; fm < 4; ++fm)
        #pragma unroll
        for (int fn = 0; fn < 4; ++fn)
          acc[fm][fn] = __builtin_amdgcn_mfma_f32_16x16x32_bf16(
              bfv[fn], af[fm], acc[fm][fn], 0, 0, 0);

      __syncthreads();
    }

    // ---- prefetch next tile's first K-step (latency hidden by epilogue) ----
    if (t4 + 1 < TPB) stage(0, 0, (tc0 + t4 + 1) << 7);

    // ---- epilogue: plain f32x4 stores (L2-absorbed, drain under next tile) --
    #pragma unroll
    for (int fm = 0; fm < 4; ++fm) {
      const int i = brow + wm * 64 + fm * 16 + (lane & 15);
      const float an = asq[i];
      float* crow = C + (size_t)i * ND;
      #pragma unroll
      for (int fn = 0; fn < 4; ++fn) {
        const int j0 = bcol + wn * 64 + fn * 16 + ((lane >> 4) << 2);
        const f32x4 b4 = *(const f32x4*)&bsq[j0];
        f32x4 o;
        o[0] = exp2f(fmaxf(an + b4[0] - 2.0f * acc[fm][fn][0], 0.0f) * cexp);
        o[1] = exp2f(fmaxf(an + b4[1] - 2.0f * acc[fm][fn][1], 0.0f) * cexp);
        o[2] = exp2f(fmaxf(an + b4[2] - 2.0f * acc[fm][fn][2], 0.0f) * cexp);
        o[3] = exp2f(fmaxf(an + b4[3] - 2.0f * acc[fm][fn][3], 0.0f) * cexp);
        *(f32x4*)&crow[j0] = o;
      }
    }

    if (t4 + 1 < TPB) __syncthreads();   // next tile's kt=0 staged + stores acked
  }
}

// ---------------------------------------------------------------------------
extern "C" void kernel_launch(void* const* d_in, const int* in_sizes, int n_in,
                              void* d_out, int out_size, void* d_ws, size_t ws_size,
                              hipStream_t stream) {
  const float* A = (const float*)d_in[0];
  const float* B = (const float*)d_in[1];
  float* C = (float*)d_out;

  const size_t bfBytes = (size_t)ND * KD * 2;   // 4 MiB per matrix
  const size_t normBytes = (size_t)ND * 4;
  char* ws = (char*)d_ws;
  const int grid = (ND / BM) * (ND / BN) / TPB;  // 1024

  if (ws_size >= 2 * bfBytes + 2 * normBytes) {
    unsigned short* Abf = (unsigned short*)ws;
    unsigned short* Bbf = (unsigned short*)(ws + bfBytes);
    float* asq = (float*)(ws + 2 * bfBytes);
    float* bsq = (float*)(ws + 2 * bfBytes + normBytes);
    hipLaunchKernelGGL(norm_convert_kernel, dim3(2 * ND / 4), dim3(256), 0, stream,
                       A, B, Abf, Bbf, asq, bsq);
    hipLaunchKernelGGL((rbf_gemm_kernel<true>), dim3(grid), dim3(256), 0,
                       stream, (const void*)Abf, (const void*)Bbf, asq, bsq, C);
  } else {
    float* asq = (float*)ws;
    float* bsq = (float*)(ws + normBytes);
    hipLaunchKernelGGL(norm_convert_kernel, dim3(2 * ND / 4), dim3(256), 0, stream,
                       A, B, (unsigned short*)nullptr, (unsigned short*)nullptr, asq, bsq);
    hipLaunchKernelGGL((rbf_gemm_kernel<false>), dim3(grid), dim3(256), 0,
                       stream, (const void*)A, (const void*)B, asq, bsq, C);
  }
}